// Round 14
// baseline (135.927 us; speedup 1.0000x reference)
//
#include <hip/hip_runtime.h>

#define BB 4
#define CIN 128
#define T3 384
#define HH 128
#define WW 128
#define NPIX 16384
#define QKV_ELE (BB*T3*NPIX)
#define NCHUNK 16

// MFMA packed-image geometry
#define SEC 4160
#define KGP 1040
#define PLN 520
// B tile (k4, 64-wide)
#define KGPB 520
#define PLNB 260

typedef __attribute__((ext_vector_type(8))) short bf16x8;
typedef __attribute__((ext_vector_type(4))) float f32x4;

__device__ __forceinline__ unsigned splitpack(float x) {
  unsigned u = __float_as_uint(x);
  unsigned hb = (u + 0x7fffu + ((u >> 16) & 1u)) >> 16;
  float lo = x - __uint_as_float(hb << 16);
  unsigned ul = __float_as_uint(lo);
  unsigned lb = (ul + 0x7fffu + ((ul >> 16) & 1u)) >> 16;
  return (hb << 16) | (lb & 0xffffu);
}

__device__ __forceinline__ void packpair(float a, float b, unsigned& hi, unsigned& lo) {
  unsigned p0 = splitpack(a), p1 = splitpack(b);
  hi = (p1 & 0xffff0000u) | (p0 >> 16);
  lo = (p1 << 16) | (p0 & 0xffffu);
}

// ============================================================================
// K0: pre-pack wqkv into MFMA image; zero zbuf.
// ============================================================================
__global__ __launch_bounds__(256) void k0_wprep(const float* __restrict__ wqkv,
                                                unsigned* __restrict__ wimg,
                                                float* __restrict__ zbuf) {
  int id = blockIdx.x * 256 + threadIdx.x;   // 0..24575
  if (id < 16) zbuf[id] = 0.f;
  int i = id & 3;
  int co = (id >> 2) & 127;
  int kgrp = (id >> 9) & 3;
  int c = (id >> 11) & 3;
  int m = id >> 13;
  int ci = c * 32 + kgrp * 8 + 2 * i;
  const float* wrow = wqkv + (size_t)(m * 128 + co) * 128 + ci;
  unsigned hi, lo;
  packpair(wrow[0], wrow[1], hi, lo);
  size_t base = (size_t)(m * 4 + c) * SEC + kgrp * KGP + co * 4 + i;
  wimg[base] = hi;
  wimg[base + PLN] = lo;
}

// ============================================================================
// K1: qkv = W @ X via split-bf16 MFMA, software-pipelined (R13-proven).
// ============================================================================
__global__ __launch_bounds__(256) void k1_qkv_mfma(const float* __restrict__ x,
                                                   const unsigned* __restrict__ wimg,
                                                   float* __restrict__ qkv) {
  __shared__ __align__(16) unsigned Xp[4 * KGP];
  __shared__ __align__(16) unsigned Wp[4 * KGP];
  const int t = threadIdx.x;
  const int p = blockIdx.x;
  const int qd = p / 24;
  const int r_ = p - qd * 24;
  const int m = r_ >> 3;
  const int tt = qd * 8 + (r_ & 7);
  const int n0 = (tt & 127) * 128;
  const int b = tt >> 7;
  const float* xb = x + (size_t)b * CIN * NPIX + n0;

  const int l = t & 63;
  const int w = t >> 6;
  const int g = l >> 4;
  const int lc = l & 15;
  const int ch = w >> 1;
  const int nh = w & 1;
  const int kg = t >> 6;
  const int nn_ = t & 63;

  f32x4 acc[4][4];
  #pragma unroll
  for (int i = 0; i < 4; ++i)
    #pragma unroll
    for (int j = 0; j < 4; ++j) acc[i][j] = (f32x4){0.f, 0.f, 0.f, 0.f};

  uint4 wpre[5];
  float xpre[16];

  {
    const uint4* wsrc = (const uint4*)(wimg + (size_t)(m * 4 + 0) * SEC);
    #pragma unroll
    for (int r = 0; r < 5; ++r) {
      int idx = t + r * 256;
      uint4 v = make_uint4(0u, 0u, 0u, 0u);
      if (idx < 1040) v = wsrc[idx];
      wpre[r] = v;
    }
    const float* colbase = xb + (size_t)(kg * 8) * NPIX;
    #pragma unroll
    for (int half = 0; half < 2; ++half) {
      const float* colp = colbase + nn_ + half * 64;
      #pragma unroll
      for (int i = 0; i < 8; ++i)
        xpre[half * 8 + i] = colp[(size_t)i * NPIX];
    }
  }

  for (int c = 0; c < 4; ++c) {
    {
      uint4* wdst = (uint4*)Wp;
      #pragma unroll
      for (int r = 0; r < 5; ++r) {
        int idx = t + r * 256;
        if (idx < 1040) wdst[idx] = wpre[r];
      }
      #pragma unroll
      for (int half = 0; half < 2; ++half) {
        int n = nn_ + half * 64;
        unsigned hp[4], lp[4];
        #pragma unroll
        for (int i = 0; i < 4; ++i)
          packpair(xpre[half * 8 + 2 * i], xpre[half * 8 + 2 * i + 1], hp[i], lp[i]);
        *(uint4*)&Xp[kg * KGP + n * 4] = make_uint4(hp[0], hp[1], hp[2], hp[3]);
        *(uint4*)&Xp[kg * KGP + PLN + n * 4] = make_uint4(lp[0], lp[1], lp[2], lp[3]);
      }
    }
    __syncthreads();

    if (c < 3) {
      const uint4* wsrc = (const uint4*)(wimg + (size_t)(m * 4 + c + 1) * SEC);
      #pragma unroll
      for (int r = 0; r < 5; ++r) {
        int idx = t + r * 256;
        uint4 v = make_uint4(0u, 0u, 0u, 0u);
        if (idx < 1040) v = wsrc[idx];
        wpre[r] = v;
      }
      const float* colbase = xb + (size_t)((c + 1) * 32 + kg * 8) * NPIX;
      #pragma unroll
      for (int half = 0; half < 2; ++half) {
        const float* colp = colbase + nn_ + half * 64;
        #pragma unroll
        for (int i = 0; i < 8; ++i)
          xpre[half * 8 + i] = colp[(size_t)i * NPIX];
      }
    }

    bf16x8 bh[4], bl[4];
    #pragma unroll
    for (int ng = 0; ng < 4; ++ng) {
      const int nb = (nh * 64 + ng * 16 + lc) * 4;
      bh[ng] = *(const bf16x8*)&Xp[g * KGP + nb];
      bl[ng] = *(const bf16x8*)&Xp[g * KGP + PLN + nb];
    }
    #pragma unroll
    for (int cg = 0; cg < 4; ++cg) {
      const int cb = (ch * 64 + cg * 16 + lc) * 4;
      bf16x8 ah = *(const bf16x8*)&Wp[g * KGP + cb];
      bf16x8 al = *(const bf16x8*)&Wp[g * KGP + PLN + cb];
      #pragma unroll
      for (int ng = 0; ng < 4; ++ng) {
        acc[cg][ng] = __builtin_amdgcn_mfma_f32_16x16x32_bf16(ah, bh[ng], acc[cg][ng], 0, 0, 0);
        acc[cg][ng] = __builtin_amdgcn_mfma_f32_16x16x32_bf16(ah, bl[ng], acc[cg][ng], 0, 0, 0);
        acc[cg][ng] = __builtin_amdgcn_mfma_f32_16x16x32_bf16(al, bh[ng], acc[cg][ng], 0, 0, 0);
      }
    }
    __syncthreads();
  }
  #pragma unroll
  for (int cg = 0; cg < 4; ++cg) {
    const size_t corow = (size_t)b * T3 + m * 128 + ch * 64 + cg * 16 + g * 4;
    #pragma unroll
    for (int ng = 0; ng < 4; ++ng) {
      const int nn = n0 + nh * 64 + ng * 16 + lc;
      #pragma unroll
      for (int rr = 0; rr < 4; ++rr)
        qkv[(corow + rr) * NPIX + nn] = acc[cg][ng][rr];
    }
  }
}

// ============================================================================
// vk wave reduce body (shared by fat-kernel qkv path and k3_agg).
// Identical math/order to R11's k3_vk.
// ============================================================================
__device__ __forceinline__ void k3_body(const float* __restrict__ base,
                                        float* __restrict__ part,
                                        int chunk, int bh, int t) {
  const float* kb = base + 8 * NPIX;
  const float* vb = base + 16 * NPIX;
  const int wv = t >> 6;
  const int lane = t & 63;
  const int d0 = wv * 2;

  float accA[8], accB[8], accS[8];
  #pragma unroll
  for (int e = 0; e < 8; ++e) { accA[e] = 0.f; accB[e] = 0.f; accS[e] = 0.f; }

  int p = chunk * (NPIX / NCHUNK) + lane;
  for (int it = 0; it < (NPIX / NCHUNK / 64); ++it, p += 64) {
    float kvv[8];
    #pragma unroll
    for (int e = 0; e < 8; ++e) kvv[e] = fmaxf(kb[(size_t)e * NPIX + p], 0.f);
    float vA = vb[(size_t)d0 * NPIX + p];
    float vB = vb[(size_t)(d0 + 1) * NPIX + p];
    #pragma unroll
    for (int e = 0; e < 8; ++e) { accA[e] += vA * kvv[e]; accB[e] += vB * kvv[e]; }
    if (wv == 0) {
      #pragma unroll
      for (int e = 0; e < 8; ++e) accS[e] += kvv[e];
    }
  }
  #pragma unroll
  for (int e = 0; e < 8; ++e) {
    #pragma unroll
    for (int m = 1; m < 64; m <<= 1) {
      accA[e] += __shfl_xor(accA[e], m);
      accB[e] += __shfl_xor(accB[e], m);
    }
  }
  if (wv == 0) {
    #pragma unroll
    for (int e = 0; e < 8; ++e)
      #pragma unroll
      for (int m = 1; m < 64; m <<= 1) accS[e] += __shfl_xor(accS[e], m);
  }
  if (lane == 0) {
    float* pr = part + ((size_t)bh * NCHUNK + chunk) * 72;
    #pragma unroll
    for (int e = 0; e < 8; ++e) {
      pr[d0 * 8 + e] = accA[e];
      pr[(d0 + 1) * 8 + e] = accB[e];
    }
    if (wv == 0) {
      #pragma unroll
      for (int e = 0; e < 8; ++e) pr[64 + e] = accS[e];
    }
  }
}

// ============================================================================
// K2 FAT: grid 7168. Per XCD-residue r=id&7, ordinal o=id>>3:
//   o < 128   -> k3-qkv-half block (q = r*128+o): vk partial, reads qkv only.
//   o >= 128  -> k2 dwpw block with L = r*768 + (o-128)  [same L-set + XCD
//                mapping as the proven split k2; body byte-identical].
// k3 blocks dispatch first -> overlap k2's idle HBM/VALU capacity.
// ============================================================================
#define PDW 36
__global__ __launch_bounds__(256, 2) void k2_fat(const float* __restrict__ qkv,
                                                 const float* __restrict__ wdw,
                                                 const float* __restrict__ wpw,
                                                 const float* __restrict__ zbuf,
                                                 float* __restrict__ agg,
                                                 float* __restrict__ part) {
  __shared__ __align__(16) float dws[8 * 16 * PDW];
  __shared__ float wds[8][25];
  __shared__ float wps[64];
  const int t = threadIdx.x;
  const int id = blockIdx.x;        // 0..7167
  const int r_ = id & 7;
  const int o_ = id >> 3;           // 0..895

  if (o_ < 128) {  // ---- k3 qkv-half path ----
    const int q = r_ * 128 + o_;    // 0..1023
    const int chunk = q & 15;
    const int bhq = q >> 4;         // 0..63
    const int b = bhq >> 4;
    const int h = bhq & 15;
    const float* base = qkv + ((size_t)b * T3 + h * 24) * NPIX;
    k3_body(base, part, chunk, b * 32 + h, t);
    return;
  }

  // ---- k2 dwpw path (proven R11 body) ----
  const int L = r_ * 768 + (o_ - 128);  // 0..6143
  const int z = L >> 5;
  const int rem = L & 31;
  const int x0 = (rem & 3) * 32;
  const int y0 = (rem >> 2) * 16;
  const int b = z / 48;
  const int g = z % 48;
  const float* src = qkv + ((size_t)b * T3 + g * 8) * NPIX;

  for (int idx = t; idx < 200; idx += 256)
    wds[idx / 25][idx % 25] = wdw[(size_t)g * 200 + idx];
  if (t < 64) wps[t] = wpw[g * 64 + t];
  __syncthreads();

  const int ch = t >> 5;
  const int xq = t & 7;
  const int yg = (t >> 3) & 3;
  const float* plane = src + (size_t)ch * NPIX;
  const int gx0 = x0 + 4 * xq - 4;
  const bool ex0 = (gx0 >= 0);
  const bool ex2 = (gx0 + 11 < WW);

  f32x4 u[8][3];
  #pragma unroll
  for (int r = 0; r < 8; ++r) {
    const int gy = y0 + 4 * yg - 2 + r;
    const bool iny = (unsigned)gy < (unsigned)HH;
    const float* rp = plane + gy * WW + gx0;
    const float* p0 = (iny && ex0) ? rp : zbuf;
    const float* p1 = iny ? (rp + 4) : zbuf;
    const float* p2 = (iny && ex2) ? (rp + 8) : zbuf;
    u[r][0] = *(const f32x4*)p0;
    u[r][1] = *(const f32x4*)p1;
    u[r][2] = *(const f32x4*)p2;
  }

  float dacc[4][4];
  #pragma unroll
  for (int jy = 0; jy < 4; ++jy)
    #pragma unroll
    for (int jx = 0; jx < 4; ++jx) dacc[jy][jx] = 0.f;

  #pragma unroll
  for (int r = 0; r < 8; ++r) {
    float vals[12] = {u[r][0][0], u[r][0][1], u[r][0][2], u[r][0][3],
                      u[r][1][0], u[r][1][1], u[r][1][2], u[r][1][3],
                      u[r][2][0], u[r][2][1], u[r][2][2], u[r][2][3]};
    #pragma unroll
    for (int jy = 0; jy < 4; ++jy) {
      int ky = r - jy;
      if (ky < 0 || ky > 4) continue;
      #pragma unroll
      for (int kx = 0; kx < 5; ++kx) {
        float wv = wds[ch][ky * 5 + kx];
        #pragma unroll
        for (int jx = 0; jx < 4; ++jx)
          dacc[jy][jx] += wv * vals[jx + kx + 2];
      }
    }
  }

  #pragma unroll
  for (int jy = 0; jy < 4; ++jy) {
    float4 o = make_float4(dacc[jy][0], dacc[jy][1], dacc[jy][2], dacc[jy][3]);
    *(float4*)&dws[ch * (16 * PDW) + (yg * 4 + jy) * PDW + xq * 4] = o;
  }
  __syncthreads();

  float* dst = agg + ((size_t)b * T3 + g * 8) * NPIX + (size_t)y0 * WW + x0;
  #pragma unroll
  for (int pp = 0; pp < 2; ++pp) {
    int pix = t + pp * 256;
    int py = pix >> 5;
    int px = pix & 31;
    float dv[8];
    #pragma unroll
    for (int ic = 0; ic < 8; ++ic) dv[ic] = dws[ic * (16 * PDW) + py * PDW + px];
    #pragma unroll
    for (int oc = 0; oc < 8; ++oc) {
      float s = 0.f;
      #pragma unroll
      for (int ic = 0; ic < 8; ++ic) s += wps[oc * 8 + ic] * dv[ic];
      dst[(size_t)oc * NPIX + py * WW + px] = s;
    }
  }
}

// ============================================================================
// K3agg: agg-half vk partials (h >= 16). Same body, grid (16, 64).
// ============================================================================
__global__ __launch_bounds__(256) void k3_agg(const float* __restrict__ agg,
                                              float* __restrict__ part) {
  const int chunk = blockIdx.x;
  const int bhq = blockIdx.y;     // 0..63
  const int b = bhq >> 4;
  const int hh = bhq & 15;
  const float* base = agg + ((size_t)b * T3 + hh * 24) * NPIX;
  k3_body(base, part, chunk, b * 32 + 16 + hh, threadIdx.x);
}

__global__ __launch_bounds__(128) void k3b_sum(const float* __restrict__ part,
                                               float* __restrict__ vk) {
  const int bh = blockIdx.x;
  const int j = threadIdx.x;
  if (j < 72) {
    float s = 0.f;
    #pragma unroll
    for (int c = 0; c < NCHUNK; ++c) s += part[((size_t)bh * NCHUNK + c) * 72 + j];
    vk[(size_t)bh * 72 + j] = s;
  }
}

// ============================================================================
// K3c: M' image + shift (unchanged)
// ============================================================================
__global__ __launch_bounds__(256) void k3c_M(const float* __restrict__ wproj,
                                             const float* __restrict__ vk,
                                             const float* __restrict__ gamma,
                                             const float* __restrict__ beta,
                                             const float* __restrict__ mean,
                                             const float* __restrict__ var,
                                             unsigned* __restrict__ Mimg,
                                             float* __restrict__ shiftb) {
  int id = blockIdx.x * 256 + threadIdx.x;
  int i = id & 3;
  int co = (id >> 2) & 127;
  int kgrp = (id >> 9) & 3;
  int cidx = (id >> 11) & 7;
  int b = id >> 14;
  int h = cidx * 4 + kgrp;
  float inv = gamma[co] * rsqrtf(var[co] + 1e-5f);
  const float* wrow = wproj + (size_t)co * 256 + h * 8;
  const float* vkc = vk + ((size_t)b * 32 + h) * 72;
  float s0 = 0.f, s1 = 0.f;
  #pragma unroll
  for (int d = 0; d < 8; ++d) {
    float wv = wrow[d];
    s0 += wv * vkc[d * 8 + 2 * i];
    s1 += wv * vkc[d * 8 + 2 * i + 1];
  }
  unsigned hi, lo;
  packpair(inv * s0, inv * s1, hi, lo);
  size_t base = (size_t)(b * 8 + cidx) * SEC + kgrp * KGP + co * 4 + i;
  Mimg[base] = hi;
  Mimg[base + PLN] = lo;
  if (b == 0 && cidx == 0 && kgrp == 0 && i == 0)
    shiftb[co] = beta[co] - mean[co] * inv;
}

// ============================================================================
// K4: out = M' @ Q' + shift, 64-wide n-tiles, software-pipelined (R13-proven).
// ============================================================================
__global__ __launch_bounds__(256) void k4_mfma(const float* __restrict__ qkv,
                                               const float* __restrict__ agg,
                                               const float* __restrict__ vk,
                                               const unsigned* __restrict__ Mimg,
                                               const float* __restrict__ shiftb,
                                               float* __restrict__ out) {
  __shared__ __align__(16) unsigned Ap[4 * KGP];
  __shared__ __align__(16) unsigned Bp[4 * KGPB];
  const int t = threadIdx.x;
  const int n0 = blockIdx.x * 64;
  const int b = blockIdx.y;

  const int l = t & 63;
  const int w = t >> 6;
  const int g = l >> 4;
  const int lc = l & 15;
  const int ch = w >> 1;
  const int nh = w & 1;
  const int hj = t >> 6;
  const int nn_ = t & 63;

  f32x4 acc[4][2];
  #pragma unroll
  for (int i = 0; i < 4; ++i)
    #pragma unroll
    for (int j = 0; j < 2; ++j) acc[i][j] = (f32x4){0.f, 0.f, 0.f, 0.f};

  uint4 apre[5];
  float qpre[8];
  float vv[8];

  {
    const uint4* asrc = (const uint4*)(Mimg + (size_t)(b * 8 + 0) * SEC);
    #pragma unroll
    for (int r = 0; r < 5; ++r) {
      int idx = t + r * 256;
      uint4 v = make_uint4(0u, 0u, 0u, 0u);
      if (idx < 1040) v = asrc[idx];
      apre[r] = v;
    }
    const int h = hj;
    const float* srcb = (h < 16 ? qkv : agg) +
                        ((size_t)b * T3 + (h & 15) * 24) * NPIX + n0 + nn_;
    const float* vkr = vk + ((size_t)b * 32 + h) * 72 + 64;
    #pragma unroll
    for (int e = 0; e < 8; ++e) {
      qpre[e] = srcb[(size_t)e * NPIX];
      vv[e] = vkr[e];
    }
  }

  for (int cidx = 0; cidx < 8; ++cidx) {
    {
      uint4* adst = (uint4*)Ap;
      #pragma unroll
      for (int r = 0; r < 5; ++r) {
        int idx = t + r * 256;
        if (idx < 1040) adst[idx] = apre[r];
      }
    }
    {
      float q[8];
      float den = 1e-15f;
      #pragma unroll
      for (int e = 0; e < 8; ++e) {
        q[e] = fmaxf(qpre[e], 0.f);
        den += vv[e] * q[e];
      }
      float rd = 1.0f / den;
      unsigned hp[4], lp[4];
      #pragma unroll
      for (int i = 0; i < 4; ++i)
        packpair(q[2 * i] * rd, q[2 * i + 1] * rd, hp[i], lp[i]);
      *(uint4*)&Bp[hj * KGPB + nn_ * 4] = make_uint4(hp[0], hp[1], hp[2], hp[3]);
      *(uint4*)&Bp[hj * KGPB + PLNB + nn_ * 4] = make_uint4(lp[0], lp[1], lp[2], lp[3]);
    }
    __syncthreads();

    if (cidx < 7) {
      const uint4* asrc = (const uint4*)(Mimg + (size_t)(b * 8 + cidx + 1) * SEC);
      #pragma unroll
      for (int r = 0; r < 5; ++r) {
        int idx = t + r * 256;
        uint4 v = make_uint4(0u, 0u, 0u, 0u);
        if (idx < 1040) v = asrc[idx];
        apre[r] = v;
      }
      const int h = (cidx + 1) * 4 + hj;
      const float* srcb = (h < 16 ? qkv : agg) +
                          ((size_t)b * T3 + (h & 15) * 24) * NPIX + n0 + nn_;
      const float* vkr = vk + ((size_t)b * 32 + h) * 72 + 64;
      #pragma unroll
      for (int e = 0; e < 8; ++e) {
        qpre[e] = srcb[(size_t)e * NPIX];
        vv[e] = vkr[e];
      }
    }

    bf16x8 bhf[2], blf[2];
    #pragma unroll
    for (int ng = 0; ng < 2; ++ng) {
      const int nb = (nh * 32 + ng * 16 + lc) * 4;
      bhf[ng] = *(const bf16x8*)&Bp[g * KGPB + nb];
      blf[ng] = *(const bf16x8*)&Bp[g * KGPB + PLNB + nb];
    }
    #pragma unroll
    for (int cg = 0; cg < 4; ++cg) {
      const int cb = (ch * 64 + cg * 16 + lc) * 4;
      bf16x8 ah = *(const bf16x8*)&Ap[g * KGP + cb];
      bf16x8 al = *(const bf16x8*)&Ap[g * KGP + PLN + cb];
      #pragma unroll
      for (int ng = 0; ng < 2; ++ng) {
        acc[cg][ng] = __builtin_amdgcn_mfma_f32_16x16x32_bf16(ah, bhf[ng], acc[cg][ng], 0, 0, 0);
        acc[cg][ng] = __builtin_amdgcn_mfma_f32_16x16x32_bf16(ah, blf[ng], acc[cg][ng], 0, 0, 0);
        acc[cg][ng] = __builtin_amdgcn_mfma_f32_16x16x32_bf16(al, bhf[ng], acc[cg][ng], 0, 0, 0);
      }
    }
    __syncthreads();
  }
  #pragma unroll
  for (int cg = 0; cg < 4; ++cg) {
    const int cobase = ch * 64 + cg * 16 + g * 4;
    #pragma unroll
    for (int ng = 0; ng < 2; ++ng) {
      const int nn = n0 + nh * 32 + ng * 16 + lc;
      #pragma unroll
      for (int rr = 0; rr < 4; ++rr) {
        int co = cobase + rr;
        out[((size_t)b * 128 + co) * NPIX + nn] = acc[cg][ng][rr] + shiftb[co];
      }
    }
  }
}

__global__ void fill_sentinel(float* o, int n) {
  int i = blockIdx.x * 256 + threadIdx.x;
  if (i < n) o[i] = 12345.0f;
}

extern "C" void kernel_launch(void* const* d_in, const int* in_sizes, int n_in,
                              void* d_out, int out_size, void* d_ws, size_t ws_size,
                              hipStream_t stream) {
  const float* x     = (const float*)d_in[0];
  const float* wqkv  = (const float*)d_in[1];
  const float* wdw   = (const float*)d_in[2];
  const float* wpw   = (const float*)d_in[3];
  const float* wproj = (const float*)d_in[4];
  const float* gamma = (const float*)d_in[5];
  const float* beta  = (const float*)d_in[6];
  const float* mean  = (const float*)d_in[7];
  const float* var   = (const float*)d_in[8];
  float* out = (float*)d_out;
  float* ws = (float*)d_ws;

  const size_t partF = 128 * NCHUNK * 72;        // 147456
  const size_t mimgF = 32 * SEC;                 // 133120
  const size_t wimgF = 12 * SEC;                 // 49920
  const size_t needF = (size_t)QKV_ELE * 2 + partF + 9216 + 128 + mimgF + wimgF + 16;
  if (ws_size < needF * 4) {
    fill_sentinel<<<dim3((out_size + 255) / 256), dim3(256), 0, stream>>>(out, out_size);
    return;
  }
  float* qkv    = ws;
  float* agg    = qkv + QKV_ELE;
  float* part   = agg + QKV_ELE;
  float* vkbuf  = part + partF;
  float* shiftb = vkbuf + 9216;
  unsigned* Mimg = (unsigned*)(shiftb + 128);
  unsigned* wimg = Mimg + mimgF;
  float* zbuf   = (float*)(wimg + wimgF);

  k0_wprep<<<dim3(96), 256, 0, stream>>>(wqkv, wimg, zbuf);
  k1_qkv_mfma<<<dim3(1536), 256, 0, stream>>>(x, wimg, qkv);
  k2_fat<<<dim3(7168), 256, 0, stream>>>(qkv, wdw, wpw, zbuf, agg, part);
  k3_agg<<<dim3(16, 64), 256, 0, stream>>>(agg, part);
  k3b_sum<<<dim3(128), 128, 0, stream>>>(part, vkbuf);
  k3c_M<<<dim3(256), 256, 0, stream>>>(wproj, vkbuf, gamma, beta, mean, var, Mimg, shiftb);
  k4_mfma<<<dim3(256, 4), 256, 0, stream>>>(qkv, agg, vkbuf, Mimg, shiftb, out);
}